// Round 1
// baseline (1931.951 us; speedup 1.0000x reference)
//
#include <hip/hip_runtime.h>
#include <cstdint>
#include <cstddef>

// Problem constants (fixed by setup_inputs)
constexpr int kB  = 2;        // batch
constexpr int kQ  = 100;      // queries
constexpr int kN  = 200000;   // points
constexpr int kI  = 64;       // instances
constexpr int kC1 = 6;        // classes + 1 (no-object)

// ---------------------------------------------------------------------------
// prep: per-batch label histogram (cnt) + first occurrence index (firstIdx)
// int atomics -> fully deterministic.
// ---------------------------------------------------------------------------
__global__ void prep_kernel(const int* __restrict__ labels,
                            int* __restrict__ cnt, int* __restrict__ firstIdx) {
  const int b = blockIdx.y;
  const int tid = threadIdx.x;
  __shared__ int lcnt[kI], lmin[kI];
  if (tid < kI) { lcnt[tid] = 0; lmin[tid] = 0x7FFFFFFF; }
  __syncthreads();
  for (int n = blockIdx.x * blockDim.x + tid; n < kN; n += gridDim.x * blockDim.x) {
    int l = labels[(size_t)b * kN + n] & (kI - 1);
    atomicAdd(&lcnt[l], 1);
    atomicMin(&lmin[l], n);
  }
  __syncthreads();
  if (tid < kI) {
    if (lcnt[tid]) atomicAdd(&cnt[b * kI + tid], lcnt[tid]);
    atomicMin(&firstIdx[b * kI + tid], lmin[tid]);
  }
}

// ---------------------------------------------------------------------------
// bucket: per (b,q), segmented sums over N points into I=64 buckets:
//   fS[i] = sum_{label==i} (pos - neg),  pS[i] = sum_{label==i} sigmoid(x)
//   negTot = sum_n neg,  pTot = sum_n sigmoid(x)
// Then cost row: costT[b][i][q] = (fS+negTot)/N + 1 - (2 pS+1)/(pTot+cnt+1)
// ---------------------------------------------------------------------------
__global__ __launch_bounds__(1024) void bucket_kernel(
    const float* __restrict__ pm, const int* __restrict__ labels,
    const int* __restrict__ cnt,
    float* __restrict__ fS, float* __restrict__ pS,
    float* __restrict__ negTot, float* __restrict__ pTot,
    float* __restrict__ costT) {
  const int q = blockIdx.x, b = blockIdx.y;
  const int tid = threadIdx.x;
  const int w = tid >> 6;

  __shared__ float lfS[16][kI];  // per-wave copies to cut atomic contention
  __shared__ float lpS[16][kI];
  ((float*)lfS)[tid] = 0.f;
  ((float*)lpS)[tid] = 0.f;
  __syncthreads();

  const float4* row4 = (const float4*)(pm + ((size_t)(b * kQ + q)) * kN);
  const int4*   lab4 = (const int4*)(labels + (size_t)b * kN);
  float negAcc = 0.f;
  constexpr int NV4 = kN / 4;

  for (int it = tid; it < NV4; it += 1024) {
    float4 xv = row4[it];
    int4   lv = lab4[it];
#define PROC(x_, l_) do {                                   \
      float x = (x_); int l = (l_) & (kI - 1);              \
      float xc = fminf(fmaxf(x, -60.f), 60.f);              \
      float t  = __expf(-xc);                               \
      float r  = 1.0f / (1.0f + t);   /* sigmoid(x) */      \
      float L  = __logf(1.0f + t);    /* softplus(-x) */    \
      float omp = t * r;              /* 1 - p */           \
      float pos = 0.25f * omp * omp * L;                    \
      float neg = 0.75f * r * r * (L + x); /* softplus(x)=x+L */ \
      atomicAdd(&lfS[w][l], pos - neg);                     \
      atomicAdd(&lpS[w][l], r);                             \
      negAcc += neg;                                        \
    } while (0)
    PROC(xv.x, lv.x); PROC(xv.y, lv.y); PROC(xv.z, lv.z); PROC(xv.w, lv.w);
#undef PROC
  }
  __syncthreads();

  __shared__ float ffS[kI], fpS[kI];
  if (tid < 2 * kI) {
    int bucket = tid & (kI - 1);
    float s = 0.f;
    if (tid < kI) { for (int ww = 0; ww < 16; ++ww) s += lfS[ww][bucket]; ffS[bucket] = s; }
    else          { for (int ww = 0; ww < 16; ++ww) s += lpS[ww][bucket]; fpS[bucket] = s; }
  }
  // negTot: wave shuffle reduce then cross-wave
  for (int off = 32; off; off >>= 1) negAcc += __shfl_down(negAcc, off);
  __shared__ float wsum[16];
  if ((tid & 63) == 0) wsum[w] = negAcc;
  __syncthreads();
  __shared__ float s_negTot, s_pTot;
  if (tid == 0) {
    float s = 0.f;
    for (int ww = 0; ww < 16; ++ww) s += wsum[ww];
    s_negTot = s;
  }
  if (tid < kI) {  // wave 0 reduces pTot from final buckets
    float v = fpS[tid];
    for (int off = 32; off; off >>= 1) v += __shfl_down(v, off);
    if (tid == 0) s_pTot = v;
  }
  __syncthreads();

  if (tid < kI) {
    float f = ffS[tid], pp = fpS[tid];
    int bq = b * kQ + q;
    fS[(size_t)bq * kI + tid] = f;
    pS[(size_t)bq * kI + tid] = pp;
    float cf = (f + s_negTot) * (1.0f / kN);
    float cd = 1.0f - (2.0f * pp + 1.0f) / (s_pTot + (float)cnt[b * kI + tid] + 1.0f);
    costT[(size_t)(b * kI + tid) * kQ + q] = cf + cd;
    if (tid == 0) { negTot[bq] = s_negTot; pTot[bq] = s_pTot; }
  }
}

// ---------------------------------------------------------------------------
// Hungarian (exact, shortest augmenting path) — mirrors the reference in f64,
// including np.argmin first-index tie-break. One wave per batch, columns
// parallelized across 64 lanes. cost is [I][Q] (i.e. reference's cost.T).
// ---------------------------------------------------------------------------
__global__ void hungarian_kernel(const float* __restrict__ costT,
                                 int* __restrict__ idx_q) {
  const int b = blockIdx.x;
  const float* cost = costT + (size_t)b * kI * kQ;
  const int lane = threadIdx.x;  // 64 threads = 1 wave
  __shared__ double u[kI + 1], v[kQ + 1], minv[kQ + 1];
  __shared__ int p[kQ + 1], way[kQ + 1], used[kQ + 1];
  __shared__ int s_j0;
  __shared__ double s_delta;
  const double INF = 1e18;

  for (int j = lane; j <= kQ; j += 64) { v[j] = 0.0; p[j] = 0; way[j] = 0; }
  u[lane] = 0.0;
  if (lane == 0) u[kI] = 0.0;
  __syncthreads();

  for (int i = 1; i <= kI; ++i) {
    if (lane == 0) { p[0] = i; s_j0 = 0; }
    for (int j = lane; j <= kQ; j += 64) { minv[j] = INF; used[j] = 0; }
    __syncthreads();
    while (true) {
      int j0 = s_j0;
      if (lane == 0) used[j0] = 1;
      __syncthreads();
      int i0 = p[j0];
      double ui0 = u[i0];
      double bestv = INF; int bestj = 0x7FFFFFFF;
      for (int j = 1 + lane; j <= kQ; j += 64) {
        if (!used[j]) {
          double cur = (double)cost[(size_t)(i0 - 1) * kQ + (j - 1)] - ui0 - v[j];
          if (cur < minv[j]) { minv[j] = cur; way[j] = j0; }
          double mv = minv[j];
          if (mv < bestv || (mv == bestv && j < bestj)) { bestv = mv; bestj = j; }
        }
      }
      for (int off = 32; off; off >>= 1) {   // first-index argmin reduce
        double ov = __shfl_down(bestv, off);
        int    oj = __shfl_down(bestj, off);
        if (ov < bestv || (ov == bestv && oj < bestj)) { bestv = ov; bestj = oj; }
      }
      if (lane == 0) { s_delta = bestv; s_j0 = bestj; }
      __syncthreads();
      double delta = s_delta;
      int j1 = s_j0;
      for (int j = lane; j <= kQ; j += 64) {
        if (used[j]) { u[p[j]] += delta; v[j] -= delta; }  // p[j] distinct rows
        else minv[j] -= delta;
      }
      __syncthreads();
      if (p[j1] == 0) break;
    }
    if (lane == 0) {  // augment
      int j0 = s_j0;
      while (j0) { int j1 = way[j0]; p[j0] = p[j1]; j0 = j1; }
    }
    __syncthreads();
  }
  for (int j = 1 + lane; j <= kQ; j += 64) {
    int pi = p[j];
    if (pi > 0) idx_q[b * kI + (pi - 1)] = j - 1;
  }
}

// ---------------------------------------------------------------------------
// final loss from bucket sums + matching
// ---------------------------------------------------------------------------
__device__ __forceinline__ float reduce128(float v, float* scratch, int tid) {
  for (int off = 32; off; off >>= 1) v += __shfl_down(v, off);
  __syncthreads();
  if ((tid & 63) == 0) scratch[tid >> 6] = v;
  __syncthreads();
  return scratch[0] + scratch[1];
}

__global__ void loss_kernel(const float* __restrict__ logits, const int* __restrict__ seg,
                            const float* __restrict__ fS, const float* __restrict__ pS,
                            const float* __restrict__ negTot, const float* __restrict__ pTot,
                            const int* __restrict__ cnt, const int* __restrict__ firstIdx,
                            const int* __restrict__ idx_q, float* __restrict__ out) {
  const int tid = threadIdx.x;  // 128
  __shared__ float lse[kQ];
  __shared__ int matched[kQ];
  __shared__ float scratch[2];
  float total = 0.f;
  for (int b = 0; b < kB; ++b) {
    if (tid < kQ) {
      const float* lr = logits + (size_t)(b * kQ + tid) * kC1;
      float m = lr[0];
#pragma unroll
      for (int c = 1; c < kC1; ++c) m = fmaxf(m, lr[c]);
      float s = 0.f;
#pragma unroll
      for (int c = 0; c < kC1; ++c) s += __expf(lr[c] - m);
      lse[tid] = m + __logf(s);
      matched[tid] = 0;
    }
    __syncthreads();
    if (tid < kI) matched[idx_q[b * kI + tid]] = 1;
    __syncthreads();

    float fo = 0.f, di = 0.f, cm = 0.f, no = 0.f, nu = 0.f;
    if (tid < kI) {
      int qi = idx_q[b * kI + tid];
      int bq = b * kQ + qi;
      float f = fS[(size_t)bq * kI + tid];
      fo = f + negTot[bq];
      float pp = pS[(size_t)bq * kI + tid];
      di = 1.f - (2.f * pp + 1.f) / (pTot[bq] + (float)cnt[b * kI + tid] + 1.f);
      int fi = firstIdx[b * kI + tid];
      fi = fi < kN ? fi : kN - 1;
      int ci = seg[(size_t)b * kN + fi];
      ci = ci < 0 ? 0 : (ci > kC1 - 2 ? kC1 - 2 : ci);  // clip(·,0,C-1)
      cm = logits[(size_t)bq * kC1 + ci] - lse[qi];
    }
    if (tid < kQ && !matched[tid]) {
      no = logits[(size_t)(b * kQ + tid) * kC1 + (kC1 - 1)] - lse[tid];
      nu = 1.f;
    }
    float foS = reduce128(fo, scratch, tid);
    float diS = reduce128(di, scratch, tid);
    float cmS = reduce128(cm, scratch, tid);
    float noS = reduce128(no, scratch, tid);
    float nuS = reduce128(nu, scratch, tid);

    float focal = foS / ((float)kI * (float)kN);
    float dice  = diS / (float)kI;
    float cem   = -cmS / (float)kI;
    float cen   = -noS / fmaxf(nuS, 1.f);
    total += focal + dice + 2.0f * cem + 0.1f * cen;
    __syncthreads();
  }
  if (tid == 0) out[0] = total * (1.0f / kB);
}

// ---------------------------------------------------------------------------
extern "C" void kernel_launch(void* const* d_in, const int* in_sizes, int n_in,
                              void* d_out, int out_size, void* d_ws, size_t ws_size,
                              hipStream_t stream) {
  const float* pm     = (const float*)d_in[0];  // [B,Q,N]
  const float* logits = (const float*)d_in[1];  // [B,Q,C1]
  const int*   labels = (const int*)d_in[2];    // [B,N]
  const int*   seg    = (const int*)d_in[3];    // [B,N]
  // d_in[4] = num_instances (compile-time kI=64)

  char* w = (char*)d_ws;
  float* fS       = (float*)w; w += (size_t)kB * kQ * kI * 4;
  float* pS       = (float*)w; w += (size_t)kB * kQ * kI * 4;
  float* negTot   = (float*)w; w += (size_t)kB * kQ * 4;
  float* pTot     = (float*)w; w += (size_t)kB * kQ * 4;
  float* costT    = (float*)w; w += (size_t)kB * kI * kQ * 4;
  int*   cnt      = (int*)w;   w += (size_t)kB * kI * 4;
  int*   firstIdx = (int*)w;   w += (size_t)kB * kI * 4;
  int*   idx_q    = (int*)w;   w += (size_t)kB * kI * 4;

  hipMemsetAsync(cnt, 0, (size_t)kB * kI * 4, stream);
  hipMemsetAsync(firstIdx, 0x7F, (size_t)kB * kI * 4, stream);  // large sentinel

  prep_kernel<<<dim3(32, kB), 256, 0, stream>>>(labels, cnt, firstIdx);
  bucket_kernel<<<dim3(kQ, kB), 1024, 0, stream>>>(pm, labels, cnt, fS, pS,
                                                   negTot, pTot, costT);
  hungarian_kernel<<<kB, 64, 0, stream>>>(costT, idx_q);
  loss_kernel<<<1, 128, 0, stream>>>(logits, seg, fS, pS, negTot, pTot,
                                     cnt, firstIdx, idx_q, (float*)d_out);
}

// Round 3
// 1225.946 us; speedup vs baseline: 1.5759x; 1.5759x over previous
//
#include <hip/hip_runtime.h>
#include <cstdint>
#include <cstddef>

// Problem constants (fixed by setup_inputs)
constexpr int kB  = 2;        // batch
constexpr int kQ  = 100;      // queries
constexpr int kN  = 200000;   // points
constexpr int kI  = 64;       // instances
constexpr int kC1 = 6;        // classes + 1 (no-object)

// ---------------------------------------------------------------------------
// prep: per-batch label histogram (cnt) + first occurrence index (firstIdx)
// ---------------------------------------------------------------------------
__global__ void prep_kernel(const int* __restrict__ labels,
                            int* __restrict__ cnt, int* __restrict__ firstIdx) {
  const int b = blockIdx.y;
  const int tid = threadIdx.x;
  __shared__ int lcnt[kI], lmin[kI];
  if (tid < kI) { lcnt[tid] = 0; lmin[tid] = 0x7FFFFFFF; }
  __syncthreads();
  for (int n = blockIdx.x * blockDim.x + tid; n < kN; n += gridDim.x * blockDim.x) {
    int l = labels[(size_t)b * kN + n] & (kI - 1);
    atomicAdd(&lcnt[l], 1);
    atomicMin(&lmin[l], n);
  }
  __syncthreads();
  if (tid < kI) {
    if (lcnt[tid]) atomicAdd(&cnt[b * kI + tid], lcnt[tid]);
    atomicMin(&firstIdx[b * kI + tid], lmin[tid]);
  }
}

// ---------------------------------------------------------------------------
// bucket: per (b,q), segmented sums over N points into I=64 buckets:
//   fS[i] = sum_{label==i} (pos - neg),  pS[i] = sum_{label==i} sigmoid(x)
//   negTot = sum_n neg,  pTot = sum_n sigmoid(x)
// Then cost row: costT[b][i][q] = (fS+negTot)/N + 1 - (2 pS+1)/(pTot+cnt+1)
// ---------------------------------------------------------------------------
__global__ __launch_bounds__(1024) void bucket_kernel(
    const float* __restrict__ pm, const int* __restrict__ labels,
    const int* __restrict__ cnt,
    float* __restrict__ fS, float* __restrict__ pS,
    float* __restrict__ negTot, float* __restrict__ pTot,
    float* __restrict__ costT) {
  const int q = blockIdx.x, b = blockIdx.y;
  const int tid = threadIdx.x;
  const int w = tid >> 6;

  __shared__ float lfS[16][kI];  // per-wave copies to cut atomic contention
  __shared__ float lpS[16][kI];
  ((float*)lfS)[tid] = 0.f;
  ((float*)lpS)[tid] = 0.f;
  __syncthreads();

  const float4* row4 = (const float4*)(pm + ((size_t)(b * kQ + q)) * kN);
  const int4*   lab4 = (const int4*)(labels + (size_t)b * kN);
  float negAcc = 0.f;
  constexpr int NV4 = kN / 4;

  for (int it = tid; it < NV4; it += 1024) {
    float4 xv = row4[it];
    int4   lv = lab4[it];
#define PROC(x_, l_) do {                                   \
      float x = (x_); int l = (l_) & (kI - 1);              \
      float xc = fminf(fmaxf(x, -60.f), 60.f);              \
      float t  = __expf(-xc);                               \
      float r  = 1.0f / (1.0f + t);   /* sigmoid(x) */      \
      float L  = __logf(1.0f + t);    /* softplus(-x) */    \
      float omp = t * r;              /* 1 - p */           \
      float pos = 0.25f * omp * omp * L;                    \
      float neg = 0.75f * r * r * (L + x); /* softplus(x)=x+L */ \
      atomicAdd(&lfS[w][l], pos - neg);                     \
      atomicAdd(&lpS[w][l], r);                             \
      negAcc += neg;                                        \
    } while (0)
    PROC(xv.x, lv.x); PROC(xv.y, lv.y); PROC(xv.z, lv.z); PROC(xv.w, lv.w);
#undef PROC
  }
  __syncthreads();

  __shared__ float ffS[kI], fpS[kI];
  if (tid < 2 * kI) {
    int bucket = tid & (kI - 1);
    float s = 0.f;
    if (tid < kI) { for (int ww = 0; ww < 16; ++ww) s += lfS[ww][bucket]; ffS[bucket] = s; }
    else          { for (int ww = 0; ww < 16; ++ww) s += lpS[ww][bucket]; fpS[bucket] = s; }
  }
  for (int off = 32; off; off >>= 1) negAcc += __shfl_down(negAcc, off);
  __shared__ float wsum[16];
  if ((tid & 63) == 0) wsum[w] = negAcc;
  __syncthreads();
  __shared__ float s_negTot, s_pTot;
  if (tid == 0) {
    float s = 0.f;
    for (int ww = 0; ww < 16; ++ww) s += wsum[ww];
    s_negTot = s;
  }
  if (tid < kI) {
    float vv = fpS[tid];
    for (int off = 32; off; off >>= 1) vv += __shfl_down(vv, off);
    if (tid == 0) s_pTot = vv;
  }
  __syncthreads();

  if (tid < kI) {
    float f = ffS[tid], pp = fpS[tid];
    int bq = b * kQ + q;
    fS[(size_t)bq * kI + tid] = f;
    pS[(size_t)bq * kI + tid] = pp;
    float cf = (f + s_negTot) * (1.0f / kN);
    float cd = 1.0f - (2.0f * pp + 1.0f) / (s_pTot + (float)cnt[b * kI + tid] + 1.0f);
    costT[(size_t)(b * kI + tid) * kQ + q] = cf + cd;
    if (tid == 0) { negTot[bq] = s_negTot; pTot[bq] = s_pTot; }
  }
}

// ---------------------------------------------------------------------------
// Hungarian — exact shortest-augmenting-path with JV greedy init.
// One wave per batch. State in registers: lane L owns columns j=1+L, j=65+L
// (v, minv, way, used, p per slot) and row L+1 (u, onpath). Cost in LDS
// (read-only; no barriers in the hot loop). Argmin via DPP/swizzle butterfly.
// Exactness: f64 arithmetic, first-index tie-break; greedy init = feasible
// duals + tight partial matching => same (a.s. unique) optimal assignment.
// Per-lane writes of uniform values use exec-predicated updates
// (if (lane==tgt) x = val) since __builtin_amdgcn_writelane is unavailable.
// ---------------------------------------------------------------------------
template<int CTRL>
__device__ __forceinline__ int dpp_mov(int x) {
  return __builtin_amdgcn_update_dpp(x, x, CTRL, 0xF, 0xF, false);
}
template<int CTRL>
__device__ __forceinline__ void bfly_dpp(double& v, int& j) {
  int lo = __double2loint(v), hi = __double2hiint(v);
  int plo = dpp_mov<CTRL>(lo), phi = dpp_mov<CTRL>(hi), pj = dpp_mov<CTRL>(j);
  double pv = __hiloint2double(phi, plo);
  if (pv < v || (pv == v && pj < j)) { v = pv; j = pj; }
}
__device__ __forceinline__ void bfly_swz16(double& v, int& j) {
  int lo = __double2loint(v), hi = __double2hiint(v);
  int plo = __builtin_amdgcn_ds_swizzle(lo, 0x401F);  // xor 16 (within 32)
  int phi = __builtin_amdgcn_ds_swizzle(hi, 0x401F);
  int pj  = __builtin_amdgcn_ds_swizzle(j,  0x401F);
  double pv = __hiloint2double(phi, plo);
  if (pv < v || (pv == v && pj < j)) { v = pv; j = pj; }
}
__device__ __forceinline__ void bfly_x32(double& v, int& j) {
  double pv = __shfl_xor(v, 32, 64);
  int    pj = __shfl_xor(j, 32, 64);
  if (pv < v || (pv == v && pj < j)) { v = pv; j = pj; }
}

__global__ void hungarian_kernel(const float* __restrict__ costT,
                                 int* __restrict__ idx_q) {
  const int b = blockIdx.x;
  const int lane = threadIdx.x;  // 64 threads = 1 wave
  __shared__ float costL[kI * kQ];
  for (int t = lane; t < kI * kQ; t += 64)
    costL[t] = costT[(size_t)b * kI * kQ + t];
  __syncthreads();

  const double INF = 1e18;
  double v0 = 0.0, v1 = 0.0;     // v[1+lane], v[65+lane]
  int p0 = 0, p1 = 0;            // p[1+lane], p[65+lane] (matched row, 1-based)
  const int slot1_valid = (lane < kQ - 64);

  // JV init: u[row] = row min; greedy-claim free argmin columns
  double m = INF; int jm = 0;
  for (int k = 0; k < kQ; ++k) {
    double c = (double)costL[lane * kQ + k];
    if (c < m) { m = c; jm = k; }          // first-index min
  }
  double u_r = m;                           // u[lane+1]
  unsigned long long rowM = 0ull;
  for (int r = 0; r < kI; ++r) {
    int jmr = __builtin_amdgcn_readlane(jm, r);   // 0..99, uniform
    int curp;
    if (jmr < 64) curp = __builtin_amdgcn_readlane(p0, jmr);
    else          curp = __builtin_amdgcn_readlane(p1, jmr - 64);
    if (curp == 0) {
      if (jmr < 64) { if (lane == jmr)      p0 = r + 1; }
      else          { if (lane == jmr - 64) p1 = r + 1; }
      rowM |= 1ull << r;
    }
  }

  // SAP for unmatched rows
  for (int i = 1; i <= kI; ++i) {
    if ((rowM >> (i - 1)) & 1ull) continue;
    double minv0 = INF, minv1 = INF;
    int way0 = 0, way1 = 0, used0 = 0, used1 = 0;
    int onpath = (lane == i - 1);
    int j0 = 0, j1 = 0;
    for (int guard = 0; guard < 2 * kQ; ++guard) {
      int i0;
      if (j0 == 0)       i0 = i;
      else if (j0 <= 64) i0 = __builtin_amdgcn_readlane(p0, j0 - 1);
      else               i0 = __builtin_amdgcn_readlane(p1, j0 - 65);
      int ulo = __builtin_amdgcn_readlane(__double2loint(u_r), i0 - 1);
      int uhi = __builtin_amdgcn_readlane(__double2hiint(u_r), i0 - 1);
      double ui0 = __hiloint2double(uhi, ulo);
      const float* crow = &costL[(i0 - 1) * kQ];
      double cur0 = (double)crow[lane] - ui0 - v0;
      if (!used0 && cur0 < minv0) { minv0 = cur0; way0 = j0; }
      double cand0 = used0 ? INF : minv0;
      double cand1 = INF;
      if (slot1_valid) {
        double cur1 = (double)crow[lane + 64] - ui0 - v1;
        if (!used1 && cur1 < minv1) { minv1 = cur1; way1 = j0; }
        if (!used1) cand1 = minv1;
      }
      double bv; int bj;
      if (cand1 < cand0) { bv = cand1; bj = lane + 65; }
      else               { bv = cand0; bj = lane + 1; }
      bfly_dpp<0xB1>(bv, bj);    // xor 1 (quad_perm 1,0,3,2)
      bfly_dpp<0x4E>(bv, bj);    // xor 2 (quad_perm 2,3,0,1)
      bfly_dpp<0x141>(bv, bj);   // xor 4 (row_half_mirror; quads uniform)
      bfly_dpp<0x140>(bv, bj);   // xor 8 (row_mirror; octets uniform)
      bfly_swz16(bv, bj);        // xor 16
      bfly_x32(bv, bj);          // xor 32
      j1 = __builtin_amdgcn_readfirstlane(bj);
      double delta = bv;         // uniform across lanes after full butterfly
      u_r += onpath ? delta : 0.0;
      if (used0) v0 -= delta; else minv0 -= delta;
      if (slot1_valid) { if (used1) v1 -= delta; else minv1 -= delta; }
      if (j1 <= 64) { if (lane == j1 - 1)  used0 = 1; }
      else          { if (lane == j1 - 65) used1 = 1; }
      int r1;
      if (j1 <= 64) r1 = __builtin_amdgcn_readlane(p0, j1 - 1);
      else          r1 = __builtin_amdgcn_readlane(p1, j1 - 65);
      if (r1 == 0) break;        // free column reached
      if (lane == r1 - 1) onpath = 1;
      j0 = j1;
    }
    // augment along way-chain (all indices/values uniform)
    int jc = j1;
    while (jc) {
      int jw;
      if (jc <= 64) jw = __builtin_amdgcn_readlane(way0, jc - 1);
      else          jw = __builtin_amdgcn_readlane(way1, jc - 65);
      int pw;
      if (jw == 0)       pw = i;
      else if (jw <= 64) pw = __builtin_amdgcn_readlane(p0, jw - 1);
      else               pw = __builtin_amdgcn_readlane(p1, jw - 65);
      if (jc <= 64) { if (lane == jc - 1)  p0 = pw; }
      else          { if (lane == jc - 65) p1 = pw; }
      jc = jw;
    }
  }
  if (p0 > 0) idx_q[b * kI + (p0 - 1)] = lane;           // j-1 = lane
  if (slot1_valid && p1 > 0) idx_q[b * kI + (p1 - 1)] = lane + 64;
}

// ---------------------------------------------------------------------------
// final loss from bucket sums + matching
// ---------------------------------------------------------------------------
__device__ __forceinline__ float reduce128(float v, float* scratch, int tid) {
  for (int off = 32; off; off >>= 1) v += __shfl_down(v, off);
  __syncthreads();
  if ((tid & 63) == 0) scratch[tid >> 6] = v;
  __syncthreads();
  return scratch[0] + scratch[1];
}

__global__ void loss_kernel(const float* __restrict__ logits, const int* __restrict__ seg,
                            const float* __restrict__ fS, const float* __restrict__ pS,
                            const float* __restrict__ negTot, const float* __restrict__ pTot,
                            const int* __restrict__ cnt, const int* __restrict__ firstIdx,
                            const int* __restrict__ idx_q, float* __restrict__ out) {
  const int tid = threadIdx.x;  // 128
  __shared__ float lse[kQ];
  __shared__ int matched[kQ];
  __shared__ float scratch[2];
  float total = 0.f;
  for (int b = 0; b < kB; ++b) {
    if (tid < kQ) {
      const float* lr = logits + (size_t)(b * kQ + tid) * kC1;
      float m = lr[0];
#pragma unroll
      for (int c = 1; c < kC1; ++c) m = fmaxf(m, lr[c]);
      float s = 0.f;
#pragma unroll
      for (int c = 0; c < kC1; ++c) s += __expf(lr[c] - m);
      lse[tid] = m + __logf(s);
      matched[tid] = 0;
    }
    __syncthreads();
    if (tid < kI) matched[idx_q[b * kI + tid]] = 1;
    __syncthreads();

    float fo = 0.f, di = 0.f, cm = 0.f, no = 0.f, nu = 0.f;
    if (tid < kI) {
      int qi = idx_q[b * kI + tid];
      int bq = b * kQ + qi;
      float f = fS[(size_t)bq * kI + tid];
      fo = f + negTot[bq];
      float pp = pS[(size_t)bq * kI + tid];
      di = 1.f - (2.f * pp + 1.f) / (pTot[bq] + (float)cnt[b * kI + tid] + 1.f);
      int fi = firstIdx[b * kI + tid];
      fi = fi < kN ? fi : kN - 1;
      int ci = seg[(size_t)b * kN + fi];
      ci = ci < 0 ? 0 : (ci > kC1 - 2 ? kC1 - 2 : ci);  // clip(·,0,C-1)
      cm = logits[(size_t)bq * kC1 + ci] - lse[qi];
    }
    if (tid < kQ && !matched[tid]) {
      no = logits[(size_t)(b * kQ + tid) * kC1 + (kC1 - 1)] - lse[tid];
      nu = 1.f;
    }
    float foS = reduce128(fo, scratch, tid);
    float diS = reduce128(di, scratch, tid);
    float cmS = reduce128(cm, scratch, tid);
    float noS = reduce128(no, scratch, tid);
    float nuS = reduce128(nu, scratch, tid);

    float focal = foS / ((float)kI * (float)kN);
    float dice  = diS / (float)kI;
    float cem   = -cmS / (float)kI;
    float cen   = -noS / fmaxf(nuS, 1.f);
    total += focal + dice + 2.0f * cem + 0.1f * cen;
    __syncthreads();
  }
  if (tid == 0) out[0] = total * (1.0f / kB);
}

// ---------------------------------------------------------------------------
extern "C" void kernel_launch(void* const* d_in, const int* in_sizes, int n_in,
                              void* d_out, int out_size, void* d_ws, size_t ws_size,
                              hipStream_t stream) {
  const float* pm     = (const float*)d_in[0];  // [B,Q,N]
  const float* logits = (const float*)d_in[1];  // [B,Q,C1]
  const int*   labels = (const int*)d_in[2];    // [B,N]
  const int*   seg    = (const int*)d_in[3];    // [B,N]

  char* w = (char*)d_ws;
  float* fS       = (float*)w; w += (size_t)kB * kQ * kI * 4;
  float* pS       = (float*)w; w += (size_t)kB * kQ * kI * 4;
  float* negTot   = (float*)w; w += (size_t)kB * kQ * 4;
  float* pTot     = (float*)w; w += (size_t)kB * kQ * 4;
  float* costT    = (float*)w; w += (size_t)kB * kI * kQ * 4;
  int*   cnt      = (int*)w;   w += (size_t)kB * kI * 4;
  int*   firstIdx = (int*)w;   w += (size_t)kB * kI * 4;
  int*   idx_q    = (int*)w;   w += (size_t)kB * kI * 4;

  (void)hipMemsetAsync(cnt, 0, (size_t)kB * kI * 4, stream);
  (void)hipMemsetAsync(firstIdx, 0x7F, (size_t)kB * kI * 4, stream);

  prep_kernel<<<dim3(32, kB), 256, 0, stream>>>(labels, cnt, firstIdx);
  bucket_kernel<<<dim3(kQ, kB), 1024, 0, stream>>>(pm, labels, cnt, fS, pS,
                                                   negTot, pTot, costT);
  hungarian_kernel<<<kB, 64, 0, stream>>>(costT, idx_q);
  loss_kernel<<<1, 128, 0, stream>>>(logits, seg, fS, pS, negTot, pTot,
                                     cnt, firstIdx, idx_q, (float*)d_out);
}

// Round 4
// 477.120 us; speedup vs baseline: 4.0492x; 2.5695x over previous
//
#include <hip/hip_runtime.h>
#include <cstdint>
#include <cstddef>

// Problem constants (fixed by setup_inputs)
constexpr int kB  = 2;        // batch
constexpr int kQ  = 100;      // queries
constexpr int kN  = 200000;   // points
constexpr int kI  = 64;       // instances
constexpr int kC1 = 6;        // classes + 1 (no-object)

// ---------------------------------------------------------------------------
// prep: per-batch label histogram (cnt) + first occurrence index (firstIdx)
// ---------------------------------------------------------------------------
__global__ void prep_kernel(const int* __restrict__ labels,
                            int* __restrict__ cnt, int* __restrict__ firstIdx) {
  const int b = blockIdx.y;
  const int tid = threadIdx.x;
  __shared__ int lcnt[kI], lmin[kI];
  if (tid < kI) { lcnt[tid] = 0; lmin[tid] = 0x7FFFFFFF; }
  __syncthreads();
  for (int n = blockIdx.x * blockDim.x + tid; n < kN; n += gridDim.x * blockDim.x) {
    int l = labels[(size_t)b * kN + n] & (kI - 1);
    atomicAdd(&lcnt[l], 1);
    atomicMin(&lmin[l], n);
  }
  __syncthreads();
  if (tid < kI) {
    if (lcnt[tid]) atomicAdd(&cnt[b * kI + tid], lcnt[tid]);
    atomicMin(&firstIdx[b * kI + tid], lmin[tid]);
  }
}

// ---------------------------------------------------------------------------
// bucket: per (b,q), segmented sums over N points into I=64 buckets.
// v2: fixed-point i64 LDS atomics (native ds_add_u64) instead of f32
// atomicAdd (which compiles to a CAS loop without unsafe-fp-atomics).
// Scale 2^21: |pos-neg| <= ~46 -> i32 fits; bucket sums fit i64 easily.
// ---------------------------------------------------------------------------
__global__ __launch_bounds__(1024) void bucket_kernel(
    const float* __restrict__ pm, const int* __restrict__ labels,
    const int* __restrict__ cnt,
    float* __restrict__ fS, float* __restrict__ pS,
    float* __restrict__ negTot, float* __restrict__ pTot,
    float* __restrict__ costT) {
  const int q = blockIdx.x, b = blockIdx.y;
  const int tid = threadIdx.x;
  const int w = tid >> 6;
  constexpr float kScale = 2097152.0f;        // 2^21
  constexpr double kInv  = 1.0 / 2097152.0;

  __shared__ unsigned long long lfS[16][kI];  // per-wave copies
  __shared__ unsigned long long lpS[16][kI];
  for (int t = tid; t < 16 * kI; t += 1024) {
    ((unsigned long long*)lfS)[t] = 0ull;
    ((unsigned long long*)lpS)[t] = 0ull;
  }
  __syncthreads();

  const float4* row4 = (const float4*)(pm + ((size_t)(b * kQ + q)) * kN);
  const int4*   lab4 = (const int4*)(labels + (size_t)b * kN);
  float negAcc = 0.f;
  constexpr int NV4 = kN / 4;

  for (int it = tid; it < NV4; it += 1024) {
    float4 xv = row4[it];
    int4   lv = lab4[it];
#define PROC(x_, l_) do {                                   \
      float x = (x_); int l = (l_) & (kI - 1);              \
      float xc = fminf(fmaxf(x, -60.f), 60.f);              \
      float t  = __expf(-xc);                               \
      float r  = 1.0f / (1.0f + t);   /* sigmoid(x) */      \
      float L  = __logf(1.0f + t);    /* softplus(-x) */    \
      float omp = t * r;              /* 1 - p */           \
      float pos = 0.25f * omp * omp * L;                    \
      float neg = 0.75f * r * r * (L + x);                  \
      int fi = __float2int_rn((pos - neg) * kScale);        \
      int pi = __float2int_rn(r * kScale);                  \
      atomicAdd(&lfS[w][l], (unsigned long long)(long long)fi); \
      atomicAdd(&lpS[w][l], (unsigned long long)(long long)pi); \
      negAcc += neg;                                        \
    } while (0)
    PROC(xv.x, lv.x); PROC(xv.y, lv.y); PROC(xv.z, lv.z); PROC(xv.w, lv.w);
#undef PROC
  }
  __syncthreads();

  __shared__ float ffS[kI], fpS[kI];
  if (tid < 2 * kI) {
    int bucket = tid & (kI - 1);
    long long s = 0;
    if (tid < kI) {
      for (int ww = 0; ww < 16; ++ww) s += (long long)lfS[ww][bucket];
      ffS[bucket] = (float)((double)s * kInv);
    } else {
      for (int ww = 0; ww < 16; ++ww) s += (long long)lpS[ww][bucket];
      fpS[bucket] = (float)((double)s * kInv);
    }
  }
  for (int off = 32; off; off >>= 1) negAcc += __shfl_down(negAcc, off);
  __shared__ float wsum[16];
  if ((tid & 63) == 0) wsum[w] = negAcc;
  __syncthreads();
  __shared__ float s_negTot, s_pTot;
  if (tid == 0) {
    float s = 0.f;
    for (int ww = 0; ww < 16; ++ww) s += wsum[ww];
    s_negTot = s;
  }
  if (tid < kI) {
    float vv = fpS[tid];
    for (int off = 32; off; off >>= 1) vv += __shfl_down(vv, off);
    if (tid == 0) s_pTot = vv;
  }
  __syncthreads();

  if (tid < kI) {
    float f = ffS[tid], pp = fpS[tid];
    int bq = b * kQ + q;
    fS[(size_t)bq * kI + tid] = f;
    pS[(size_t)bq * kI + tid] = pp;
    float cf = (f + s_negTot) * (1.0f / kN);
    float cd = 1.0f - (2.0f * pp + 1.0f) / (s_pTot + (float)cnt[b * kI + tid] + 1.0f);
    costT[(size_t)(b * kI + tid) * kQ + q] = cf + cd;
    if (tid == 0) { negTot[bq] = s_negTot; pTot[bq] = s_pTot; }
  }
}

// ---------------------------------------------------------------------------
// Hungarian v3 — exact SAP with JV greedy init; per-round critical path cut
// by packing (value, column) into one f64 (all reduced costs >= 0, so value
// order == bit order; low 7 mantissa bits hold the column id => fmin does
// lexicographic (value, first-index) argmin). Butterfly: 4 DPP levels (VALU)
// + constant-lane readlane combine. No LDS-pipe ops in the argmin tail.
// ---------------------------------------------------------------------------
template<int CTRL>
__device__ __forceinline__ int dpp_mov(int x) {
  return __builtin_amdgcn_update_dpp(x, x, CTRL, 0xF, 0xF, false);
}
template<int CTRL>
__device__ __forceinline__ double dpp_min(double a) {
  int lo = dpp_mov<CTRL>(__double2loint(a));
  int hi = dpp_mov<CTRL>(__double2hiint(a));
  double o = __hiloint2double(hi, lo);
  return fmin(a, o);
}
__device__ __forceinline__ double rl64(double x, int l) {
  int lo = __builtin_amdgcn_readlane(__double2loint(x), l);
  int hi = __builtin_amdgcn_readlane(__double2hiint(x), l);
  return __hiloint2double(hi, lo);
}
__device__ __forceinline__ double packVJ(double v, int j) {
  long long bb = __double_as_longlong(v);
  bb = (bb & ~0x7FLL) | (long long)j;
  return __longlong_as_double(bb);
}
__device__ __forceinline__ double unpackV(double pv) {
  return __longlong_as_double(__double_as_longlong(pv) & ~0x7FLL);
}

__global__ void hungarian_kernel(const float* __restrict__ costT,
                                 int* __restrict__ idx_q) {
  const int b = blockIdx.x;
  const int lane = threadIdx.x;  // 64 threads = 1 wave
  __shared__ float costL[kI * kQ];
  for (int t = lane; t < kI * kQ; t += 64)
    costL[t] = costT[(size_t)b * kI * kQ + t];
  __syncthreads();

  const double INF = 1e18;
  const double INFP = packVJ(INF, 127);
  double v0 = 0.0, v1 = 0.0;     // v[1+lane], v[65+lane]
  int p0 = 0, p1 = 0;            // matched row (1-based) of cols lane+1, lane+65
  const bool s1v = (lane < kQ - 64);

  // JV greedy init: u[row]=row min; claim free argmin columns
  double m = INF; int jm = 0;
  for (int k = 0; k < kQ; ++k) {
    double c = (double)costL[lane * kQ + k];
    if (c < m) { m = c; jm = k; }            // first-index min
  }
  double u_r = m;                             // u[lane+1]
  unsigned long long rowM = 0ull;
  for (int r = 0; r < kI; ++r) {
    int jmr = __builtin_amdgcn_readlane(jm, r);
    int curp = (jmr < 64) ? __builtin_amdgcn_readlane(p0, jmr)
                          : __builtin_amdgcn_readlane(p1, jmr - 64);
    if (curp == 0) {
      if (jmr < 64) { if (lane == jmr)      p0 = r + 1; }
      else          { if (lane == jmr - 64) p1 = r + 1; }
      rowM |= 1ull << r;
    }
  }

  // SAP for unmatched rows
  for (int i = 1; i <= kI; ++i) {
    if ((rowM >> (i - 1)) & 1ull) continue;
    double minv0 = INFP, minv1 = INFP;
    int way0 = 0, way1 = 0, used0 = 0, used1 = 0;
    int onpath = (lane == i - 1) ? 1 : 0;
    int i0 = i, j0 = 0, j1 = 0;
    for (int guard = 0; guard < 2 * kQ; ++guard) {
      double ui0 = rl64(u_r, i0 - 1);
      const float* crow = &costL[(i0 - 1) * kQ];
      double cur0 = (double)crow[lane] - ui0 - v0;
      double pk0 = packVJ(cur0, lane + 1);
      if (!used0 && pk0 < minv0) { minv0 = pk0; way0 = j0; }
      if (s1v && !used1) {
        double cur1 = (double)crow[lane + 64] - ui0 - v1;
        double pk1 = packVJ(cur1, lane + 65);
        if (pk1 < minv1) { minv1 = pk1; way1 = j0; }
      }
      double bm = fmin(minv0, minv1);
      bm = dpp_min<0xB1>(bm);    // xor 1 (quad_perm 1,0,3,2)
      bm = dpp_min<0x4E>(bm);    // xor 2 (quad_perm 2,3,0,1)
      bm = dpp_min<0x141>(bm);   // xor 4 (row_half_mirror; quads uniform)
      bm = dpp_min<0x140>(bm);   // xor 8 (row_mirror; octets uniform)
      double g = fmin(fmin(rl64(bm, 0), rl64(bm, 16)),
                      fmin(rl64(bm, 32), rl64(bm, 48)));
      long long gb = __double_as_longlong(g);
      j1 = __builtin_amdgcn_readfirstlane((int)(gb & 0x7FLL));
      double delta = __longlong_as_double(gb & ~0x7FLL);

      u_r += onpath ? delta : 0.0;
      if (used0) v0 -= delta;
      else       minv0 = packVJ(unpackV(minv0) - delta, lane + 1);
      if (s1v) {
        if (used1) v1 -= delta;
        else       minv1 = packVJ(unpackV(minv1) - delta, lane + 65);
      }
      if (j1 <= 64) { if (lane == j1 - 1)  { used0 = 1; minv0 = INFP; } }
      else          { if (lane == j1 - 65) { used1 = 1; minv1 = INFP; } }

      int r1 = (j1 <= 64) ? __builtin_amdgcn_readlane(p0, j1 - 1)
                          : __builtin_amdgcn_readlane(p1, j1 - 65);
      if (r1 == 0) break;        // free column reached
      if (lane == r1 - 1) onpath = 1;
      i0 = r1;
      j0 = j1;
    }
    // augment along way-chain (all indices/values uniform)
    int jc = j1;
    while (jc) {
      int jw = (jc <= 64) ? __builtin_amdgcn_readlane(way0, jc - 1)
                          : __builtin_amdgcn_readlane(way1, jc - 65);
      int pw;
      if (jw == 0)       pw = i;
      else if (jw <= 64) pw = __builtin_amdgcn_readlane(p0, jw - 1);
      else               pw = __builtin_amdgcn_readlane(p1, jw - 65);
      if (jc <= 64) { if (lane == jc - 1)  p0 = pw; }
      else          { if (lane == jc - 65) p1 = pw; }
      jc = jw;
    }
  }
  if (p0 > 0) idx_q[b * kI + (p0 - 1)] = lane;
  if (s1v && p1 > 0) idx_q[b * kI + (p1 - 1)] = lane + 64;
}

// ---------------------------------------------------------------------------
// final loss from bucket sums + matching
// ---------------------------------------------------------------------------
__device__ __forceinline__ float reduce128(float v, float* scratch, int tid) {
  for (int off = 32; off; off >>= 1) v += __shfl_down(v, off);
  __syncthreads();
  if ((tid & 63) == 0) scratch[tid >> 6] = v;
  __syncthreads();
  return scratch[0] + scratch[1];
}

__global__ void loss_kernel(const float* __restrict__ logits, const int* __restrict__ seg,
                            const float* __restrict__ fS, const float* __restrict__ pS,
                            const float* __restrict__ negTot, const float* __restrict__ pTot,
                            const int* __restrict__ cnt, const int* __restrict__ firstIdx,
                            const int* __restrict__ idx_q, float* __restrict__ out) {
  const int tid = threadIdx.x;  // 128
  __shared__ float lse[kQ];
  __shared__ int matched[kQ];
  __shared__ float scratch[2];
  float total = 0.f;
  for (int b = 0; b < kB; ++b) {
    if (tid < kQ) {
      const float* lr = logits + (size_t)(b * kQ + tid) * kC1;
      float m = lr[0];
#pragma unroll
      for (int c = 1; c < kC1; ++c) m = fmaxf(m, lr[c]);
      float s = 0.f;
#pragma unroll
      for (int c = 0; c < kC1; ++c) s += __expf(lr[c] - m);
      lse[tid] = m + __logf(s);
      matched[tid] = 0;
    }
    __syncthreads();
    if (tid < kI) matched[idx_q[b * kI + tid]] = 1;
    __syncthreads();

    float fo = 0.f, di = 0.f, cm = 0.f, no = 0.f, nu = 0.f;
    if (tid < kI) {
      int qi = idx_q[b * kI + tid];
      int bq = b * kQ + qi;
      float f = fS[(size_t)bq * kI + tid];
      fo = f + negTot[bq];
      float pp = pS[(size_t)bq * kI + tid];
      di = 1.f - (2.f * pp + 1.f) / (pTot[bq] + (float)cnt[b * kI + tid] + 1.f);
      int fi = firstIdx[b * kI + tid];
      fi = fi < kN ? fi : kN - 1;
      int ci = seg[(size_t)b * kN + fi];
      ci = ci < 0 ? 0 : (ci > kC1 - 2 ? kC1 - 2 : ci);  // clip(·,0,C-1)
      cm = logits[(size_t)bq * kC1 + ci] - lse[qi];
    }
    if (tid < kQ && !matched[tid]) {
      no = logits[(size_t)(b * kQ + tid) * kC1 + (kC1 - 1)] - lse[tid];
      nu = 1.f;
    }
    float foS = reduce128(fo, scratch, tid);
    float diS = reduce128(di, scratch, tid);
    float cmS = reduce128(cm, scratch, tid);
    float noS = reduce128(no, scratch, tid);
    float nuS = reduce128(nu, scratch, tid);

    float focal = foS / ((float)kI * (float)kN);
    float dice  = diS / (float)kI;
    float cem   = -cmS / (float)kI;
    float cen   = -noS / fmaxf(nuS, 1.f);
    total += focal + dice + 2.0f * cem + 0.1f * cen;
    __syncthreads();
  }
  if (tid == 0) out[0] = total * (1.0f / kB);
}

// ---------------------------------------------------------------------------
extern "C" void kernel_launch(void* const* d_in, const int* in_sizes, int n_in,
                              void* d_out, int out_size, void* d_ws, size_t ws_size,
                              hipStream_t stream) {
  const float* pm     = (const float*)d_in[0];  // [B,Q,N]
  const float* logits = (const float*)d_in[1];  // [B,Q,C1]
  const int*   labels = (const int*)d_in[2];    // [B,N]
  const int*   seg    = (const int*)d_in[3];    // [B,N]

  char* w = (char*)d_ws;
  float* fS       = (float*)w; w += (size_t)kB * kQ * kI * 4;
  float* pS       = (float*)w; w += (size_t)kB * kQ * kI * 4;
  float* negTot   = (float*)w; w += (size_t)kB * kQ * 4;
  float* pTot     = (float*)w; w += (size_t)kB * kQ * 4;
  float* costT    = (float*)w; w += (size_t)kB * kI * kQ * 4;
  int*   cnt      = (int*)w;   w += (size_t)kB * kI * 4;
  int*   firstIdx = (int*)w;   w += (size_t)kB * kI * 4;
  int*   idx_q    = (int*)w;   w += (size_t)kB * kI * 4;

  (void)hipMemsetAsync(cnt, 0, (size_t)kB * kI * 4, stream);
  (void)hipMemsetAsync(firstIdx, 0x7F, (size_t)kB * kI * 4, stream);

  prep_kernel<<<dim3(32, kB), 256, 0, stream>>>(labels, cnt, firstIdx);
  bucket_kernel<<<dim3(kQ, kB), 1024, 0, stream>>>(pm, labels, cnt, fS, pS,
                                                   negTot, pTot, costT);
  hungarian_kernel<<<kB, 64, 0, stream>>>(costT, idx_q);
  loss_kernel<<<1, 128, 0, stream>>>(logits, seg, fS, pS, negTot, pTot,
                                     cnt, firstIdx, idx_q, (float*)d_out);
}

// Round 5
// 389.884 us; speedup vs baseline: 4.9552x; 1.2237x over previous
//
#include <hip/hip_runtime.h>
#include <cstdint>
#include <cstddef>

// Problem constants (fixed by setup_inputs)
constexpr int kB  = 2;        // batch
constexpr int kQ  = 100;      // queries
constexpr int kN  = 200000;   // points
constexpr int kI  = 64;       // instances
constexpr int kC1 = 6;        // classes + 1 (no-object)

// ---------------------------------------------------------------------------
// prep: per-batch label histogram (cnt) + first occurrence index (firstIdx)
// ---------------------------------------------------------------------------
__global__ void prep_kernel(const int* __restrict__ labels,
                            int* __restrict__ cnt, int* __restrict__ firstIdx) {
  const int b = blockIdx.y;
  const int tid = threadIdx.x;
  __shared__ int lcnt[kI], lmin[kI];
  if (tid < kI) { lcnt[tid] = 0; lmin[tid] = 0x7FFFFFFF; }
  __syncthreads();
  for (int n = blockIdx.x * blockDim.x + tid; n < kN; n += gridDim.x * blockDim.x) {
    int l = labels[(size_t)b * kN + n] & (kI - 1);
    atomicAdd(&lcnt[l], 1);
    atomicMin(&lmin[l], n);
  }
  __syncthreads();
  if (tid < kI) {
    if (lcnt[tid]) atomicAdd(&cnt[b * kI + tid], lcnt[tid]);
    atomicMin(&firstIdx[b * kI + tid], lmin[tid]);
  }
}

// ---------------------------------------------------------------------------
// bucket: per (b,q), segmented sums over N points into I=64 buckets.
// Fixed-point i64 LDS atomics (native ds_add_u64); scale 2^21.
// ---------------------------------------------------------------------------
__global__ __launch_bounds__(1024) void bucket_kernel(
    const float* __restrict__ pm, const int* __restrict__ labels,
    const int* __restrict__ cnt,
    float* __restrict__ fS, float* __restrict__ pS,
    float* __restrict__ negTot, float* __restrict__ pTot,
    float* __restrict__ costT) {
  const int q = blockIdx.x, b = blockIdx.y;
  const int tid = threadIdx.x;
  const int w = tid >> 6;
  constexpr float kScale = 2097152.0f;        // 2^21
  constexpr double kInv  = 1.0 / 2097152.0;

  __shared__ unsigned long long lfS[16][kI];  // per-wave copies
  __shared__ unsigned long long lpS[16][kI];
  for (int t = tid; t < 16 * kI; t += 1024) {
    ((unsigned long long*)lfS)[t] = 0ull;
    ((unsigned long long*)lpS)[t] = 0ull;
  }
  __syncthreads();

  const float4* row4 = (const float4*)(pm + ((size_t)(b * kQ + q)) * kN);
  const int4*   lab4 = (const int4*)(labels + (size_t)b * kN);
  float negAcc = 0.f;
  constexpr int NV4 = kN / 4;

  for (int it = tid; it < NV4; it += 1024) {
    float4 xv = row4[it];
    int4   lv = lab4[it];
#define PROC(x_, l_) do {                                   \
      float x = (x_); int l = (l_) & (kI - 1);              \
      float xc = fminf(fmaxf(x, -60.f), 60.f);              \
      float t  = __expf(-xc);                               \
      float r  = 1.0f / (1.0f + t);   /* sigmoid(x) */      \
      float L  = __logf(1.0f + t);    /* softplus(-x) */    \
      float omp = t * r;              /* 1 - p */           \
      float pos = 0.25f * omp * omp * L;                    \
      float neg = 0.75f * r * r * (L + x);                  \
      int fi = __float2int_rn((pos - neg) * kScale);        \
      int pi = __float2int_rn(r * kScale);                  \
      atomicAdd(&lfS[w][l], (unsigned long long)(long long)fi); \
      atomicAdd(&lpS[w][l], (unsigned long long)(long long)pi); \
      negAcc += neg;                                        \
    } while (0)
    PROC(xv.x, lv.x); PROC(xv.y, lv.y); PROC(xv.z, lv.z); PROC(xv.w, lv.w);
#undef PROC
  }
  __syncthreads();

  __shared__ float ffS[kI], fpS[kI];
  if (tid < 2 * kI) {
    int bucket = tid & (kI - 1);
    long long s = 0;
    if (tid < kI) {
      for (int ww = 0; ww < 16; ++ww) s += (long long)lfS[ww][bucket];
      ffS[bucket] = (float)((double)s * kInv);
    } else {
      for (int ww = 0; ww < 16; ++ww) s += (long long)lpS[ww][bucket];
      fpS[bucket] = (float)((double)s * kInv);
    }
  }
  for (int off = 32; off; off >>= 1) negAcc += __shfl_down(negAcc, off);
  __shared__ float wsum[16];
  if ((tid & 63) == 0) wsum[w] = negAcc;
  __syncthreads();
  __shared__ float s_negTot, s_pTot;
  if (tid == 0) {
    float s = 0.f;
    for (int ww = 0; ww < 16; ++ww) s += wsum[ww];
    s_negTot = s;
  }
  if (tid < kI) {
    float vv = fpS[tid];
    for (int off = 32; off; off >>= 1) vv += __shfl_down(vv, off);
    if (tid == 0) s_pTot = vv;
  }
  __syncthreads();

  if (tid < kI) {
    float f = ffS[tid], pp = fpS[tid];
    int bq = b * kQ + q;
    fS[(size_t)bq * kI + tid] = f;
    pS[(size_t)bq * kI + tid] = pp;
    float cf = (f + s_negTot) * (1.0f / kN);
    float cd = 1.0f - (2.0f * pp + 1.0f) / (s_pTot + (float)cnt[b * kI + tid] + 1.0f);
    costT[(size_t)(b * kI + tid) * kQ + q] = cf + cd;
    if (tid == 0) { negTot[bq] = s_negTot; pTot[bq] = s_pTot; }
  }
}

// ---------------------------------------------------------------------------
// Hungarian v4 — exact SAP + JV greedy init + LAPJV augmenting row reduction.
// Packed (value,column) f64 trick: reduced costs >= 0 so bit order == value
// order; low 7 mantissa bits carry the column id => fmin does lexicographic
// (value, first-index) argmin. Feasibility invariant maintained at every
// augrowred step: u[i]+v[j] <= c[i][j] for all (i,j), matched pairs tight:
//   set u[i]=min2, v[j1]-=(min2-min1) => row i: tight at j1, slack elsewhere;
//   other rows: v only decreased; kicked row i0 keeps its (feasible) u.
// Hence the final SAP on leftover rows yields the exact optimum (a.s. unique
// for continuous random costs => identical to the reference assignment).
// ---------------------------------------------------------------------------
template<int CTRL>
__device__ __forceinline__ int dpp_mov(int x) {
  return __builtin_amdgcn_update_dpp(x, x, CTRL, 0xF, 0xF, false);
}
template<int CTRL>
__device__ __forceinline__ double dpp_mov64(double a) {
  int lo = dpp_mov<CTRL>(__double2loint(a));
  int hi = dpp_mov<CTRL>(__double2hiint(a));
  return __hiloint2double(hi, lo);
}
template<int CTRL>
__device__ __forceinline__ double dpp_min(double a) {
  return fmin(a, dpp_mov64<CTRL>(a));
}
__device__ __forceinline__ double rl64(double x, int l) {
  int lo = __builtin_amdgcn_readlane(__double2loint(x), l);
  int hi = __builtin_amdgcn_readlane(__double2hiint(x), l);
  return __hiloint2double(hi, lo);
}
__device__ __forceinline__ double packVJ(double v, int j) {
  long long bb = __double_as_longlong(v);
  bb = (bb & ~0x7FLL) | (long long)j;
  return __longlong_as_double(bb);
}
__device__ __forceinline__ double unpackV(double pv) {
  return __longlong_as_double(__double_as_longlong(pv) & ~0x7FLL);
}
// two-smallest combine on packed values (packing is order-monotone)
__device__ __forceinline__ void comb2(double& m1, double& m2, double o1, double o2) {
  double lo = fmin(m1, o1);
  double hi = fmax(m1, o1);
  m2 = fmin(hi, fmin(m2, o2));
  m1 = lo;
}
template<int CTRL>
__device__ __forceinline__ void dpp_comb2(double& m1, double& m2) {
  double o1 = dpp_mov64<CTRL>(m1);
  double o2 = dpp_mov64<CTRL>(m2);
  comb2(m1, m2, o1, o2);
}

__global__ void hungarian_kernel(const float* __restrict__ costT,
                                 int* __restrict__ idx_q) {
  const int b = blockIdx.x;
  const int lane = threadIdx.x;  // 64 threads = 1 wave
  __shared__ float costL[kI * kQ];
  for (int t = lane; t < kI * kQ; t += 64)
    costL[t] = costT[(size_t)b * kI * kQ + t];
  __syncthreads();

  const double INF = 1e18;
  const double INFP = packVJ(INF, 127);
  double v0 = 0.0, v1 = 0.0;     // v[1+lane], v[65+lane]
  int p0 = 0, p1 = 0;            // matched row (1-based) of cols lane+1, lane+65
  const bool s1v = (lane < kQ - 64);

  // --- JV greedy init: u[row]=row min; claim free argmin columns ----------
  double m = INF; int jm = 0;
  for (int k = 0; k < kQ; ++k) {
    double c = (double)costL[lane * kQ + k];
    if (c < m) { m = c; jm = k; }            // first-index min
  }
  double u_r = m;                             // u[lane+1]
  unsigned long long rowM = 0ull;
  for (int r = 0; r < kI; ++r) {
    int jmr = __builtin_amdgcn_readlane(jm, r);
    int curp = (jmr < 64) ? __builtin_amdgcn_readlane(p0, jmr)
                          : __builtin_amdgcn_readlane(p1, jmr - 64);
    if (curp == 0) {
      if (jmr < 64) { if (lane == jmr)      p0 = r + 1; }
      else          { if (lane == jmr - 64) p1 = r + 1; }
      rowM |= 1ull << r;
    }
  }

  // --- LAPJV augmenting row reduction (2 bounded passes) -------------------
  unsigned long long pool = ~rowM;            // unmatched rows (bit r = row r+1)
  unsigned long long leftover = 0ull;
  for (int pass = 0; pass < 2; ++pass) {
    unsigned long long next = 0ull;
    unsigned long long cur = pool;
    while (cur) {
      int i = __builtin_ctzll(cur) + 1;       // row, 1-based
      cur &= cur - 1;
      const float* crow = &costL[(i - 1) * kQ];
      double pk0 = packVJ((double)crow[lane] - v0, lane + 1);
      double pk1 = s1v ? packVJ((double)crow[lane + 64] - v1, lane + 65) : INFP;
      double m1 = fmin(pk0, pk1), m2 = fmax(pk0, pk1);
      dpp_comb2<0xB1>(m1, m2);                // xor 1
      dpp_comb2<0x4E>(m1, m2);                // xor 2
      dpp_comb2<0x141>(m1, m2);               // xor 4
      dpp_comb2<0x140>(m1, m2);               // xor 8
      double a1 = rl64(m1, 0),  a2 = rl64(m2, 0);
      { double b1 = rl64(m1, 16), b2 = rl64(m2, 16); comb2(a1, a2, b1, b2); }
      { double b1 = rl64(m1, 32), b2 = rl64(m2, 32); comb2(a1, a2, b1, b2); }
      { double b1 = rl64(m1, 48), b2 = rl64(m2, 48); comb2(a1, a2, b1, b2); }
      long long g1 = __double_as_longlong(a1);
      int j1 = __builtin_amdgcn_readfirstlane((int)(g1 & 0x7FLL));
      double min1 = __longlong_as_double(g1 & ~0x7FLL);
      double min2 = unpackV(a2);
      double dv = min2 - min1;                // >= 0
      if (lane == i - 1) u_r = min2;          // u[i] = second minimum
      int i0;
      if (j1 <= 64) {
        i0 = __builtin_amdgcn_readlane(p0, j1 - 1);
        if (lane == j1 - 1) { p0 = i; v0 -= dv; }
      } else {
        i0 = __builtin_amdgcn_readlane(p1, j1 - 65);
        if (lane == j1 - 65) { p1 = i; v1 -= dv; }
      }
      if (i0 != 0) {                          // kicked row -> later pass / SAP
        if (pass == 0) next |= 1ull << (i0 - 1);
        else           leftover |= 1ull << (i0 - 1);
      }
    }
    pool = next;
  }
  leftover |= pool;                           // (pool empty after pass 1)

  // --- exact SAP for leftover rows ----------------------------------------
  for (int i = 1; i <= kI; ++i) {
    if (!((leftover >> (i - 1)) & 1ull)) continue;
    double minv0 = INFP, minv1 = INFP;
    int way0 = 0, way1 = 0, used0 = 0, used1 = 0;
    int onpath = (lane == i - 1) ? 1 : 0;
    int i0 = i, j0 = 0, j1 = 0;
    for (int guard = 0; guard < 2 * kQ; ++guard) {
      double ui0 = rl64(u_r, i0 - 1);
      const float* crow = &costL[(i0 - 1) * kQ];
      double cur0 = (double)crow[lane] - ui0 - v0;
      double pk0 = packVJ(cur0, lane + 1);
      if (!used0 && pk0 < minv0) { minv0 = pk0; way0 = j0; }
      if (s1v && !used1) {
        double cur1 = (double)crow[lane + 64] - ui0 - v1;
        double pk1 = packVJ(cur1, lane + 65);
        if (pk1 < minv1) { minv1 = pk1; way1 = j0; }
      }
      double bm = fmin(minv0, minv1);
      bm = dpp_min<0xB1>(bm);    // xor 1
      bm = dpp_min<0x4E>(bm);    // xor 2
      bm = dpp_min<0x141>(bm);   // xor 4
      bm = dpp_min<0x140>(bm);   // xor 8
      double g = fmin(fmin(rl64(bm, 0), rl64(bm, 16)),
                      fmin(rl64(bm, 32), rl64(bm, 48)));
      long long gb = __double_as_longlong(g);
      j1 = __builtin_amdgcn_readfirstlane((int)(gb & 0x7FLL));
      double delta = __longlong_as_double(gb & ~0x7FLL);

      u_r += onpath ? delta : 0.0;
      if (used0) v0 -= delta;
      else       minv0 = packVJ(unpackV(minv0) - delta, lane + 1);
      if (s1v) {
        if (used1) v1 -= delta;
        else       minv1 = packVJ(unpackV(minv1) - delta, lane + 65);
      }
      if (j1 <= 64) { if (lane == j1 - 1)  { used0 = 1; minv0 = INFP; } }
      else          { if (lane == j1 - 65) { used1 = 1; minv1 = INFP; } }

      int r1 = (j1 <= 64) ? __builtin_amdgcn_readlane(p0, j1 - 1)
                          : __builtin_amdgcn_readlane(p1, j1 - 65);
      if (r1 == 0) break;        // free column reached
      if (lane == r1 - 1) onpath = 1;
      i0 = r1;
      j0 = j1;
    }
    // augment along way-chain (all indices/values uniform)
    int jc = j1;
    while (jc) {
      int jw = (jc <= 64) ? __builtin_amdgcn_readlane(way0, jc - 1)
                          : __builtin_amdgcn_readlane(way1, jc - 65);
      int pw;
      if (jw == 0)       pw = i;
      else if (jw <= 64) pw = __builtin_amdgcn_readlane(p0, jw - 1);
      else               pw = __builtin_amdgcn_readlane(p1, jw - 65);
      if (jc <= 64) { if (lane == jc - 1)  p0 = pw; }
      else          { if (lane == jc - 65) p1 = pw; }
      jc = jw;
    }
  }
  if (p0 > 0) idx_q[b * kI + (p0 - 1)] = lane;
  if (s1v && p1 > 0) idx_q[b * kI + (p1 - 1)] = lane + 64;
}

// ---------------------------------------------------------------------------
// final loss from bucket sums + matching
// ---------------------------------------------------------------------------
__device__ __forceinline__ float reduce128(float v, float* scratch, int tid) {
  for (int off = 32; off; off >>= 1) v += __shfl_down(v, off);
  __syncthreads();
  if ((tid & 63) == 0) scratch[tid >> 6] = v;
  __syncthreads();
  return scratch[0] + scratch[1];
}

__global__ void loss_kernel(const float* __restrict__ logits, const int* __restrict__ seg,
                            const float* __restrict__ fS, const float* __restrict__ pS,
                            const float* __restrict__ negTot, const float* __restrict__ pTot,
                            const int* __restrict__ cnt, const int* __restrict__ firstIdx,
                            const int* __restrict__ idx_q, float* __restrict__ out) {
  const int tid = threadIdx.x;  // 128
  __shared__ float lse[kQ];
  __shared__ int matched[kQ];
  __shared__ float scratch[2];
  float total = 0.f;
  for (int b = 0; b < kB; ++b) {
    if (tid < kQ) {
      const float* lr = logits + (size_t)(b * kQ + tid) * kC1;
      float m = lr[0];
#pragma unroll
      for (int c = 1; c < kC1; ++c) m = fmaxf(m, lr[c]);
      float s = 0.f;
#pragma unroll
      for (int c = 0; c < kC1; ++c) s += __expf(lr[c] - m);
      lse[tid] = m + __logf(s);
      matched[tid] = 0;
    }
    __syncthreads();
    if (tid < kI) matched[idx_q[b * kI + tid]] = 1;
    __syncthreads();

    float fo = 0.f, di = 0.f, cm = 0.f, no = 0.f, nu = 0.f;
    if (tid < kI) {
      int qi = idx_q[b * kI + tid];
      int bq = b * kQ + qi;
      float f = fS[(size_t)bq * kI + tid];
      fo = f + negTot[bq];
      float pp = pS[(size_t)bq * kI + tid];
      di = 1.f - (2.f * pp + 1.f) / (pTot[bq] + (float)cnt[b * kI + tid] + 1.f);
      int fi = firstIdx[b * kI + tid];
      fi = fi < kN ? fi : kN - 1;
      int ci = seg[(size_t)b * kN + fi];
      ci = ci < 0 ? 0 : (ci > kC1 - 2 ? kC1 - 2 : ci);  // clip(·,0,C-1)
      cm = logits[(size_t)bq * kC1 + ci] - lse[qi];
    }
    if (tid < kQ && !matched[tid]) {
      no = logits[(size_t)(b * kQ + tid) * kC1 + (kC1 - 1)] - lse[tid];
      nu = 1.f;
    }
    float foS = reduce128(fo, scratch, tid);
    float diS = reduce128(di, scratch, tid);
    float cmS = reduce128(cm, scratch, tid);
    float noS = reduce128(no, scratch, tid);
    float nuS = reduce128(nu, scratch, tid);

    float focal = foS / ((float)kI * (float)kN);
    float dice  = diS / (float)kI;
    float cem   = -cmS / (float)kI;
    float cen   = -noS / fmaxf(nuS, 1.f);
    total += focal + dice + 2.0f * cem + 0.1f * cen;
    __syncthreads();
  }
  if (tid == 0) out[0] = total * (1.0f / kB);
}

// ---------------------------------------------------------------------------
extern "C" void kernel_launch(void* const* d_in, const int* in_sizes, int n_in,
                              void* d_out, int out_size, void* d_ws, size_t ws_size,
                              hipStream_t stream) {
  const float* pm     = (const float*)d_in[0];  // [B,Q,N]
  const float* logits = (const float*)d_in[1];  // [B,Q,C1]
  const int*   labels = (const int*)d_in[2];    // [B,N]
  const int*   seg    = (const int*)d_in[3];    // [B,N]

  char* w = (char*)d_ws;
  float* fS       = (float*)w; w += (size_t)kB * kQ * kI * 4;
  float* pS       = (float*)w; w += (size_t)kB * kQ * kI * 4;
  float* negTot   = (float*)w; w += (size_t)kB * kQ * 4;
  float* pTot     = (float*)w; w += (size_t)kB * kQ * 4;
  float* costT    = (float*)w; w += (size_t)kB * kI * kQ * 4;
  int*   cnt      = (int*)w;   w += (size_t)kB * kI * 4;
  int*   firstIdx = (int*)w;   w += (size_t)kB * kI * 4;
  int*   idx_q    = (int*)w;   w += (size_t)kB * kI * 4;

  (void)hipMemsetAsync(cnt, 0, (size_t)kB * kI * 4, stream);
  (void)hipMemsetAsync(firstIdx, 0x7F, (size_t)kB * kI * 4, stream);

  prep_kernel<<<dim3(32, kB), 256, 0, stream>>>(labels, cnt, firstIdx);
  bucket_kernel<<<dim3(kQ, kB), 1024, 0, stream>>>(pm, labels, cnt, fS, pS,
                                                   negTot, pTot, costT);
  hungarian_kernel<<<kB, 64, 0, stream>>>(costT, idx_q);
  loss_kernel<<<1, 128, 0, stream>>>(logits, seg, fS, pS, negTot, pTot,
                                     cnt, firstIdx, idx_q, (float*)d_out);
}